// Round 2
// baseline (360.126 us; speedup 1.0000x reference)
//
#include <hip/hip_runtime.h>

// QLoRA NF4 forward: out[b,s,o] = 4.0 * sum_r (sum_i x[b,s,i]*W_A[r,i]) * W_B[o,r]
// B=4 S=2048 IN=4096 OUT=4096 R=8. All fp32.
//
// R5: fused kernel, register-pressure-honest version.
//  R4 post-mortem: WRITE_SIZE=251.6MB vs out=134.2MB -> ~117MB of scratch
//  spill stores (phase 2 needed ~90 VGPRs, allocator gave 64). Fix:
//   - phase 1: R3-K1 proven shape. Wave owns 2 rows, full i-range.
//     acc0[8]+acc1[8]=16 regs, ~35 total. interm -> LDS (256 B).
//   - phase 2: interm[m][r] is THREAD-INVARIANT -> readfirstlane into
//     64 SGPRs (v_fma takes 1 SGPR operand free). VGPR need drops to
//     w[8] float4 (32) + s (4) + addr ~= 48. All 8 rows in one pass,
//     wBt read once per block. k-loop unroll 1 so w[] isn't replicated.
//  Expected: no scratch, WRITE ~= 134 MB, fused ~55-70 us.

static __device__ __constant__ float NF4_TBL[16] = {
    -1.0f, -0.6961928009986877f, -0.5250730514526367f, -0.39491748809814453f,
    -0.28444138169288635f, -0.18477343022823334f, -0.09105003625154495f, 0.0f,
    0.07958029955625534f, 0.16093020141124725f, 0.24611230194568634f,
    0.33791524171829224f, 0.44070982933044434f, 0.5626170039176941f,
    0.7229568362236328f, 1.0f};

__global__ void nf4_dequant_kernel(const int* __restrict__ codesA,
                                   const float* __restrict__ absA,
                                   const int* __restrict__ codesB,
                                   const float* __restrict__ absB,
                                   float* __restrict__ wA,    // [8][4096]
                                   float* __restrict__ wBt,   // [8][4096] transposed
                                   int n) {
    int id = blockIdx.x * blockDim.x + threadIdx.x;
    if (id < n) {
        wA[id] = NF4_TBL[codesA[id] & 15] * absA[id >> 6];
        // wBt output-linear: id = r*4096 + o. codes_B flat index = o*8 + r,
        // absmax_B index = (o*8+r)>>6 = o>>3 (r<8). Stores coalesced.
        const int r = id >> 12;
        const int o = id & 4095;
        wBt[id] = NF4_TBL[codesB[o * 8 + r] & 15] * absB[o >> 3];
    }
}

// Fused lora_a + lora_b. Block = 8 rows, 256 threads (4 waves), 1024 blocks.
__global__ __launch_bounds__(256, 4) void lora_fused_kernel(
    const float* __restrict__ x,       // [8192][4096]
    const float* __restrict__ wA,      // [8][4096]
    const float* __restrict__ wBt,     // [8][4096]
    float* __restrict__ out) {         // [8192][4096]
    __shared__ float interm_s[8][8];

    const int t    = threadIdx.x;
    const int wave = t >> 6;
    const int lane = t & 63;
    const int row0 = blockIdx.x * 8;
    const int r0   = row0 + 2 * wave;          // this wave's first row

    // ---------------- phase 1: interm = x @ wA^T (wave owns 2 rows) ------
    const float4* __restrict__ x0  = (const float4*)(x + (size_t)r0 * 4096);
    const float4* __restrict__ x1  = x0 + 1024;
    const float4* __restrict__ wA4 = (const float4*)wA;

    float acc0[8], acc1[8];
    #pragma unroll
    for (int r = 0; r < 8; ++r) { acc0[r] = 0.f; acc1[r] = 0.f; }

    #pragma unroll 4
    for (int c = 0; c < 16; ++c) {
        const int idx = lane + 64 * c;            // coalesced per wave
        const float4 xa = x0[idx];
        const float4 xb = x1[idx];
        #pragma unroll
        for (int r = 0; r < 8; ++r) {
            const float4 w = wA4[r * 1024 + idx]; // L2-resident
            acc0[r] += xa.x * w.x + xa.y * w.y + xa.z * w.z + xa.w * w.w;
            acc1[r] += xb.x * w.x + xb.y * w.y + xb.z * w.z + xb.w * w.w;
        }
    }

    #pragma unroll
    for (int r = 0; r < 8; ++r) {
        float v0 = acc0[r], v1 = acc1[r];
        #pragma unroll
        for (int off = 32; off > 0; off >>= 1) {
            v0 += __shfl_down(v0, off, 64);
            v1 += __shfl_down(v1, off, 64);
        }
        if (lane == 0) {
            interm_s[2 * wave][r]     = v0;
            interm_s[2 * wave + 1][r] = v1;
        }
    }
    __syncthreads();

    // ---------------- phase 2: out = 4 * interm @ wBt ---------------------
    // interm is thread-invariant -> hoist into SGPRs (readfirstlane).
    // v_fma_f32 takes one SGPR operand, so these cost ZERO VGPRs.
    float ims[8][8];
    #pragma unroll
    for (int m = 0; m < 8; ++m)
        #pragma unroll
        for (int r = 0; r < 8; ++r) {
            const float v = interm_s[m][r] * 4.0f;   // SCALING folded
            ims[m][r] = __int_as_float(
                __builtin_amdgcn_readfirstlane(__float_as_int(v)));
        }

    const float4* __restrict__ wt = (const float4*)wBt;   // [8][1024]

    #pragma unroll 1
    for (int k = 0; k < 4; ++k) {
        const int og = t + 256 * k;                       // float4 col group
        float4 w[8];
        #pragma unroll
        for (int r = 0; r < 8; ++r) w[r] = wt[r * 1024 + og];  // coalesced

        #pragma unroll
        for (int m = 0; m < 8; ++m) {
            float4 s;
            s.x = ims[m][0] * w[0].x + ims[m][1] * w[1].x + ims[m][2] * w[2].x
                + ims[m][3] * w[3].x + ims[m][4] * w[4].x + ims[m][5] * w[5].x
                + ims[m][6] * w[6].x + ims[m][7] * w[7].x;
            s.y = ims[m][0] * w[0].y + ims[m][1] * w[1].y + ims[m][2] * w[2].y
                + ims[m][3] * w[3].y + ims[m][4] * w[4].y + ims[m][5] * w[5].y
                + ims[m][6] * w[6].y + ims[m][7] * w[7].y;
            s.z = ims[m][0] * w[0].z + ims[m][1] * w[1].z + ims[m][2] * w[2].z
                + ims[m][3] * w[3].z + ims[m][4] * w[4].z + ims[m][5] * w[5].z
                + ims[m][6] * w[6].z + ims[m][7] * w[7].z;
            s.w = ims[m][0] * w[0].w + ims[m][1] * w[1].w + ims[m][2] * w[2].w
                + ims[m][3] * w[3].w + ims[m][4] * w[4].w + ims[m][5] * w[5].w
                + ims[m][6] * w[6].w + ims[m][7] * w[7].w;
            ((float4*)(out + (size_t)(row0 + m) * 4096))[og] = s;  // coalesced
        }
    }
}

extern "C" void kernel_launch(void* const* d_in, const int* in_sizes, int n_in,
                              void* d_out, int out_size, void* d_ws, size_t ws_size,
                              hipStream_t stream) {
    const float* x        = (const float*)d_in[0];
    const int*   codes_A  = (const int*)d_in[1];
    const float* absmax_A = (const float*)d_in[2];
    const int*   codes_B  = (const int*)d_in[3];
    const float* absmax_B = (const float*)d_in[4];
    float* out = (float*)d_out;

    constexpr int NW = 8 * 4096;                 // elements per factor
    float* wA  = (float*)d_ws;                   // 128 KB
    float* wBt = (float*)d_ws + NW;              // 128 KB (transposed)

    nf4_dequant_kernel<<<(NW + 255) / 256, 256, 0, stream>>>(
        codes_A, absmax_A, codes_B, absmax_B, wA, wBt, NW);

    lora_fused_kernel<<<8192 / 8, 256, 0, stream>>>(x, wA, wBt, out);
}

// Round 3
// 259.303 us; speedup vs baseline: 1.3888x; 1.3888x over previous
//
#include <hip/hip_runtime.h>

// QLoRA NF4 forward: out[b,s,o] = 4.0 * sum_r (sum_i x[b,s,i]*W_A[r,i]) * W_B[o,r]
// B=4 S=2048 IN=4096 OUT=4096 R=8. All fp32.
//
// R6: fused kernel, UNCAPPED registers.
//  R5 post-mortem: WRITE=288MiB (out=128MiB) with VGPR_Count=64 pinned by
//  __launch_bounds__(256,4) -> allocator spilled phase-1's pipelined loads
//  (unroll 4 = up to 40 float4 load results in flight) to scratch. The SGPR
//  hoist DID land (SGPR 32->96) but couldn't matter under a 64-VGPR cap.
//  Fix:
//   - __launch_bounds__(256) only: no occupancy floor, 256-VGPR budget.
//     At ~128 VGPR the kernel still gets 4 waves/SIMD -- enough TLP for a
//     streaming kernel; spill-freedom matters more than occupancy here.
//   - phase-1 c-loop unroll 2 (max ~20 float4 in flight = 80 VGPRs).
//   - phase 2 unchanged: interm in SGPRs via readfirstlane (proven), w[8]
//     float4 per k-group, coalesced float4 stores.
//  Verification signal: WRITE_SIZE must drop to ~131072 KB (out only).

static __device__ __constant__ float NF4_TBL[16] = {
    -1.0f, -0.6961928009986877f, -0.5250730514526367f, -0.39491748809814453f,
    -0.28444138169288635f, -0.18477343022823334f, -0.09105003625154495f, 0.0f,
    0.07958029955625534f, 0.16093020141124725f, 0.24611230194568634f,
    0.33791524171829224f, 0.44070982933044434f, 0.5626170039176941f,
    0.7229568362236328f, 1.0f};

__global__ void nf4_dequant_kernel(const int* __restrict__ codesA,
                                   const float* __restrict__ absA,
                                   const int* __restrict__ codesB,
                                   const float* __restrict__ absB,
                                   float* __restrict__ wA,    // [8][4096]
                                   float* __restrict__ wBt,   // [8][4096] transposed
                                   int n) {
    int id = blockIdx.x * blockDim.x + threadIdx.x;
    if (id < n) {
        wA[id] = NF4_TBL[codesA[id] & 15] * absA[id >> 6];
        // wBt output-linear: id = r*4096 + o. codes_B flat index = o*8 + r,
        // absmax_B index = (o*8+r)>>6 = o>>3 (r<8). Stores coalesced.
        const int r = id >> 12;
        const int o = id & 4095;
        wBt[id] = NF4_TBL[codesB[o * 8 + r] & 15] * absB[o >> 3];
    }
}

// Fused lora_a + lora_b. Block = 8 rows, 256 threads (4 waves), 1024 blocks.
// NO occupancy floor: let the allocator pipeline without spilling.
__global__ __launch_bounds__(256) void lora_fused_kernel(
    const float* __restrict__ x,       // [8192][4096]
    const float* __restrict__ wA,      // [8][4096]
    const float* __restrict__ wBt,     // [8][4096]
    float* __restrict__ out) {         // [8192][4096]
    __shared__ float interm_s[8][8];

    const int t    = threadIdx.x;
    const int wave = t >> 6;
    const int lane = t & 63;
    const int row0 = blockIdx.x * 8;
    const int r0   = row0 + 2 * wave;          // this wave's first row

    // ---------------- phase 1: interm = x @ wA^T (wave owns 2 rows) ------
    const float4* __restrict__ x0  = (const float4*)(x + (size_t)r0 * 4096);
    const float4* __restrict__ x1  = x0 + 1024;
    const float4* __restrict__ wA4 = (const float4*)wA;

    float acc0[8], acc1[8];
    #pragma unroll
    for (int r = 0; r < 8; ++r) { acc0[r] = 0.f; acc1[r] = 0.f; }

    #pragma unroll 2
    for (int c = 0; c < 16; ++c) {
        const int idx = lane + 64 * c;            // coalesced per wave
        const float4 xa = x0[idx];
        const float4 xb = x1[idx];
        #pragma unroll
        for (int r = 0; r < 8; ++r) {
            const float4 w = wA4[r * 1024 + idx]; // L2-resident
            acc0[r] += xa.x * w.x + xa.y * w.y + xa.z * w.z + xa.w * w.w;
            acc1[r] += xb.x * w.x + xb.y * w.y + xb.z * w.z + xb.w * w.w;
        }
    }

    #pragma unroll
    for (int r = 0; r < 8; ++r) {
        float v0 = acc0[r], v1 = acc1[r];
        #pragma unroll
        for (int off = 32; off > 0; off >>= 1) {
            v0 += __shfl_down(v0, off, 64);
            v1 += __shfl_down(v1, off, 64);
        }
        if (lane == 0) {
            interm_s[2 * wave][r]     = v0;
            interm_s[2 * wave + 1][r] = v1;
        }
    }
    __syncthreads();

    // ---------------- phase 2: out = 4 * interm @ wBt ---------------------
    // interm is thread-invariant -> hoist into SGPRs (readfirstlane).
    // v_fma_f32 takes one SGPR operand, so these cost ZERO VGPRs.
    float ims[8][8];
    #pragma unroll
    for (int m = 0; m < 8; ++m)
        #pragma unroll
        for (int r = 0; r < 8; ++r) {
            const float v = interm_s[m][r] * 4.0f;   // SCALING folded
            ims[m][r] = __int_as_float(
                __builtin_amdgcn_readfirstlane(__float_as_int(v)));
        }

    const float4* __restrict__ wt = (const float4*)wBt;   // [8][1024]

    #pragma unroll 1
    for (int k = 0; k < 4; ++k) {
        const int og = t + 256 * k;                       // float4 col group
        float4 w[8];
        #pragma unroll
        for (int r = 0; r < 8; ++r) w[r] = wt[r * 1024 + og];  // coalesced

        #pragma unroll
        for (int m = 0; m < 8; ++m) {
            float4 s;
            s.x = ims[m][0] * w[0].x + ims[m][1] * w[1].x + ims[m][2] * w[2].x
                + ims[m][3] * w[3].x + ims[m][4] * w[4].x + ims[m][5] * w[5].x
                + ims[m][6] * w[6].x + ims[m][7] * w[7].x;
            s.y = ims[m][0] * w[0].y + ims[m][1] * w[1].y + ims[m][2] * w[2].y
                + ims[m][3] * w[3].y + ims[m][4] * w[4].y + ims[m][5] * w[5].y
                + ims[m][6] * w[6].y + ims[m][7] * w[7].y;
            s.z = ims[m][0] * w[0].z + ims[m][1] * w[1].z + ims[m][2] * w[2].z
                + ims[m][3] * w[3].z + ims[m][4] * w[4].z + ims[m][5] * w[5].z
                + ims[m][6] * w[6].z + ims[m][7] * w[7].z;
            s.w = ims[m][0] * w[0].w + ims[m][1] * w[1].w + ims[m][2] * w[2].w
                + ims[m][3] * w[3].w + ims[m][4] * w[4].w + ims[m][5] * w[5].w
                + ims[m][6] * w[6].w + ims[m][7] * w[7].w;
            ((float4*)(out + (size_t)(row0 + m) * 4096))[og] = s;  // coalesced
        }
    }
}

extern "C" void kernel_launch(void* const* d_in, const int* in_sizes, int n_in,
                              void* d_out, int out_size, void* d_ws, size_t ws_size,
                              hipStream_t stream) {
    const float* x        = (const float*)d_in[0];
    const int*   codes_A  = (const int*)d_in[1];
    const float* absmax_A = (const float*)d_in[2];
    const int*   codes_B  = (const int*)d_in[3];
    const float* absmax_B = (const float*)d_in[4];
    float* out = (float*)d_out;

    constexpr int NW = 8 * 4096;                 // elements per factor
    float* wA  = (float*)d_ws;                   // 128 KB
    float* wBt = (float*)d_ws + NW;              // 128 KB (transposed)

    nf4_dequant_kernel<<<(NW + 255) / 256, 256, 0, stream>>>(
        codes_A, absmax_A, codes_B, absmax_B, wA, wBt, NW);

    lora_fused_kernel<<<8192 / 8, 256, 0, stream>>>(x, wA, wBt, out);
}

// Round 4
// 257.070 us; speedup vs baseline: 1.4009x; 1.0087x over previous
//
#include <hip/hip_runtime.h>

// QLoRA NF4 forward: out[b,s,o] = 4.0 * sum_r (sum_i x[b,s,i]*W_A[r,i]) * W_B[o,r]
// B=4 S=2048 IN=4096 OUT=4096 R=8. All fp32.
//
// R7: i-split phase 1 -> wA read ONCE per block (was 4x).
//  R6 post-mortem: spills fixed (WRITE==out exactly), kernel 94us but only
//  2.2 TB/s, VALUBusy 17%, occ 18% -> latency/L1-bound. Each wave streamed
//  the full 128 KiB wA (L1 doesn't hold it) = 512 KiB/block redundant L1/L2
//  traffic ~= 16us/CU of L1 occupancy in phase 1 alone.
//  Fix:
//   - wave w owns i-quarter w; lane-group (lane>>4) owns 2 rows; acc[2][8].
//     wA per block: 512->128 KiB, and each wA float4 load is broadcast
//     across the 4 lane-groups (one 256B line serves 4x the FMAs).
//   - reduction: 4-step shfl within 16 lanes + 1 KiB LDS combine.
//   - phase 2 unchanged (SGPR-resident interm via readfirstlane; proven
//     clean WRITE_SIZE). No launch_bounds floor (R6 lesson).

static __device__ __constant__ float NF4_TBL[16] = {
    -1.0f, -0.6961928009986877f, -0.5250730514526367f, -0.39491748809814453f,
    -0.28444138169288635f, -0.18477343022823334f, -0.09105003625154495f, 0.0f,
    0.07958029955625534f, 0.16093020141124725f, 0.24611230194568634f,
    0.33791524171829224f, 0.44070982933044434f, 0.5626170039176941f,
    0.7229568362236328f, 1.0f};

__global__ void nf4_dequant_kernel(const int* __restrict__ codesA,
                                   const float* __restrict__ absA,
                                   const int* __restrict__ codesB,
                                   const float* __restrict__ absB,
                                   float* __restrict__ wA,    // [8][4096]
                                   float* __restrict__ wBt,   // [8][4096] transposed
                                   int n) {
    int id = blockIdx.x * blockDim.x + threadIdx.x;
    if (id < n) {
        wA[id] = NF4_TBL[codesA[id] & 15] * absA[id >> 6];
        // wBt output-linear: id = r*4096 + o. codes_B flat index = o*8 + r,
        // absmax_B index = (o*8+r)>>6 = o>>3 (r<8). Stores coalesced.
        const int r = id >> 12;
        const int o = id & 4095;
        wBt[id] = NF4_TBL[codesB[o * 8 + r] & 15] * absB[o >> 3];
    }
}

// Fused lora_a + lora_b. Block = 8 rows, 256 threads (4 waves), 1024 blocks.
__global__ __launch_bounds__(256) void lora_fused_kernel(
    const float* __restrict__ x,       // [8192][4096]
    const float* __restrict__ wA,      // [8][4096]
    const float* __restrict__ wBt,     // [8][4096]
    float* __restrict__ out) {         // [8192][4096]
    __shared__ float p_s[4][8][8];     // per-wave partials [wave][row][r]
    __shared__ float im_s[8][8];       // combined interm

    const int t    = threadIdx.x;
    const int wave = t >> 6;
    const int lane = t & 63;
    const int g    = lane >> 4;        // lane-group: owns rows 2g, 2g+1
    const int l16  = lane & 15;
    const int row0 = blockIdx.x * 8;

    // ------- phase 1: interm = x @ wA^T (i-quarter per wave) --------------
    // wave owns i-range [wave*1024, wave*1024+1024) = 256 float4.
    const float4* __restrict__ x0 =
        (const float4*)(x + (size_t)(row0 + 2 * g) * 4096) + wave * 256;
    const float4* __restrict__ x1 = x0 + 1024;          // next row
    const float4* __restrict__ wq = (const float4*)wA + wave * 256;

    float acc0[8], acc1[8];
    #pragma unroll
    for (int r = 0; r < 8; ++r) { acc0[r] = 0.f; acc1[r] = 0.f; }

    #pragma unroll 2
    for (int s = 0; s < 16; ++s) {
        const int idx = s * 16 + l16;                   // 256B-coalesced/group
        const float4 xa = x0[idx];
        const float4 xb = x1[idx];
        #pragma unroll
        for (int r = 0; r < 8; ++r) {
            const float4 w = wq[r * 1024 + idx];        // broadcast x4 groups
            acc0[r] += xa.x * w.x + xa.y * w.y + xa.z * w.z + xa.w * w.w;
            acc1[r] += xb.x * w.x + xb.y * w.y + xb.z * w.z + xb.w * w.w;
        }
    }

    // reduce across the 16 lanes of each group
    #pragma unroll
    for (int r = 0; r < 8; ++r) {
        float v0 = acc0[r], v1 = acc1[r];
        #pragma unroll
        for (int off = 8; off > 0; off >>= 1) {
            v0 += __shfl_down(v0, off, 16);
            v1 += __shfl_down(v1, off, 16);
        }
        if (l16 == 0) {
            p_s[wave][2 * g][r]     = v0;
            p_s[wave][2 * g + 1][r] = v1;
        }
    }
    __syncthreads();

    if (t < 64) {                                       // combine 4 quarters
        const int m = t >> 3, r = t & 7;
        im_s[m][r] = (p_s[0][m][r] + p_s[1][m][r] +
                      p_s[2][m][r] + p_s[3][m][r]) * 4.0f;   // SCALING folded
    }
    __syncthreads();

    // ------- phase 2: out = interm @ wBt ----------------------------------
    // interm is thread-invariant -> hoist into SGPRs (readfirstlane);
    // v_fma_f32 takes one SGPR operand free. Proven no-spill shape.
    float ims[8][8];
    #pragma unroll
    for (int m = 0; m < 8; ++m)
        #pragma unroll
        for (int r = 0; r < 8; ++r)
            ims[m][r] = __int_as_float(
                __builtin_amdgcn_readfirstlane(__float_as_int(im_s[m][r])));

    const float4* __restrict__ wt = (const float4*)wBt;   // [8][1024]

    #pragma unroll 1
    for (int k = 0; k < 4; ++k) {
        const int og = t + 256 * k;                       // float4 col group
        float4 w[8];
        #pragma unroll
        for (int r = 0; r < 8; ++r) w[r] = wt[r * 1024 + og];  // coalesced

        #pragma unroll
        for (int m = 0; m < 8; ++m) {
            float4 s;
            s.x = ims[m][0] * w[0].x + ims[m][1] * w[1].x + ims[m][2] * w[2].x
                + ims[m][3] * w[3].x + ims[m][4] * w[4].x + ims[m][5] * w[5].x
                + ims[m][6] * w[6].x + ims[m][7] * w[7].x;
            s.y = ims[m][0] * w[0].y + ims[m][1] * w[1].y + ims[m][2] * w[2].y
                + ims[m][3] * w[3].y + ims[m][4] * w[4].y + ims[m][5] * w[5].y
                + ims[m][6] * w[6].y + ims[m][7] * w[7].y;
            s.z = ims[m][0] * w[0].z + ims[m][1] * w[1].z + ims[m][2] * w[2].z
                + ims[m][3] * w[3].z + ims[m][4] * w[4].z + ims[m][5] * w[5].z
                + ims[m][6] * w[6].z + ims[m][7] * w[7].z;
            s.w = ims[m][0] * w[0].w + ims[m][1] * w[1].w + ims[m][2] * w[2].w
                + ims[m][3] * w[3].w + ims[m][4] * w[4].w + ims[m][5] * w[5].w
                + ims[m][6] * w[6].w + ims[m][7] * w[7].w;
            ((float4*)(out + (size_t)(row0 + m) * 4096))[og] = s;  // coalesced
        }
    }
}

extern "C" void kernel_launch(void* const* d_in, const int* in_sizes, int n_in,
                              void* d_out, int out_size, void* d_ws, size_t ws_size,
                              hipStream_t stream) {
    const float* x        = (const float*)d_in[0];
    const int*   codes_A  = (const int*)d_in[1];
    const float* absmax_A = (const float*)d_in[2];
    const int*   codes_B  = (const int*)d_in[3];
    const float* absmax_B = (const float*)d_in[4];
    float* out = (float*)d_out;

    constexpr int NW = 8 * 4096;                 // elements per factor
    float* wA  = (float*)d_ws;                   // 128 KB
    float* wBt = (float*)d_ws + NW;              // 128 KB (transposed)

    nf4_dequant_kernel<<<(NW + 255) / 256, 256, 0, stream>>>(
        codes_A, absmax_A, codes_B, absmax_B, wA, wBt, NW);

    lora_fused_kernel<<<8192 / 8, 256, 0, stream>>>(x, wA, wBt, out);
}